// Round 4
// baseline (427.497 us; speedup 1.0000x reference)
//
#include <hip/hip_runtime.h>
#include <hip/hip_bf16.h>

#define D_MODEL 768
#define NSEQ    8192
#define NBATCH  4
#define MROWS   (NBATCH*NSEQ)   // 32768
#define CHUNK   128
#define NCHUNK  (NSEQ/CHUNK)    // 64

// GEMM tile: BM=BN=128, BK=32, double-buffered LDS, 4 waves 2x2, wave tile 64x64
#define BM 128
#define BN 128
#define BK 32

typedef __attribute__((ext_vector_type(8)))  short bshort8;
typedef __attribute__((ext_vector_type(16))) float f32x16;

__device__ __forceinline__ float bf2f(ushort u){
  union { unsigned int i; float f; } x; x.i = ((unsigned int)u) << 16; return x.f;
}
__device__ __forceinline__ ushort f2bf(float f){
  union { float f; unsigned int i; } x; x.f = f;
  unsigned int r = x.i + 0x7fffu + ((x.i >> 16) & 1u);
  return (ushort)(r >> 16);
}
__device__ __forceinline__ float silu_f(float v){ return v / (1.0f + __expf(-v)); }

__device__ __forceinline__ void async_copy16(const ushort* g, ushort* l){
  __builtin_amdgcn_global_load_lds((const __attribute__((address_space(1))) void*)g,
                                   (__attribute__((address_space(3))) void*)l, 16, 0, 0);
}

// ---------------- weight transpose + bf16 convert: in[R][C] f32 -> out[C][R] bf16
__global__ void tr_cvt(const float* __restrict__ in, ushort* __restrict__ out, int R, int C){
  __shared__ float tile[32][33];
  int c0 = blockIdx.x*32, r0 = blockIdx.y*32;
  int tx = threadIdx.x & 31, ty = threadIdx.x >> 5;
  #pragma unroll
  for (int p=0;p<4;p++){
    int r = ty + p*8;
    tile[r][tx] = in[(size_t)(r0+r)*C + c0 + tx];
  }
  __syncthreads();
  #pragma unroll
  for (int p=0;p<4;p++){
    int c = ty + p*8;
    out[(size_t)(c0+c)*R + r0 + tx] = f2bf(tile[tx][c]);
  }
}

// ---------------- x fp32 -> bf16, 8 elems/thread, 16B stores
__global__ void cvt_bf16(const float* __restrict__ in, ushort* __restrict__ out, int n){
  int i = (blockIdx.x*256 + threadIdx.x)*8;
  if (i >= n) return;
  const float4 f0 = *(const float4*)(in + i);
  const float4 f1 = *(const float4*)(in + i + 4);
  ushort o[8];
  o[0]=f2bf(f0.x); o[1]=f2bf(f0.y); o[2]=f2bf(f0.z); o[3]=f2bf(f0.w);
  o[4]=f2bf(f1.x); o[5]=f2bf(f1.y); o[6]=f2bf(f1.z); o[7]=f2bf(f1.w);
  *(ulonglong2*)(out + i) = *(const ulonglong2*)o;
}

// ---------------- bf16 GEMM, 128x128 tile, BK=32, 32x32x16 MFMA, 2-stage LDS pipeline.
// A[M][K] bf16 row-major, BT[N][K] bf16 row-major.
// LDS buffer: row r (32 ushorts) = 4 chunks of 8; physical chunk cp holds logical
// cl = cp ^ ((r>>1)&3)  (spreads 8-lane phase groups across all 32 banks on read).
// MODE 0: N=1536, block cols uniform: bn<6 -> xc bf16; bn>=6 -> silu -> z bf16
// MODE 1: N=768, fp32 out
template<int MODE>
__global__ __launch_bounds__(256, 4) void gemm_bt(
    const ushort* __restrict__ A, const ushort* __restrict__ BT,
    ushort* __restrict__ oxc, ushort* __restrict__ oz, float* __restrict__ of,
    int K)
{
  __shared__ __align__(16) ushort Asm[2*BM*BK];  // 2 x 8 KB
  __shared__ __align__(16) ushort Bsm[2*BM*BK];  // 2 x 8 KB
  const int tid = threadIdx.x;
  const int bm = blockIdx.x, bn = blockIdx.y;
  const int lane = tid & 63, wid = tid >> 6;
  const int wm = (wid >> 1) * 64, wn = (wid & 1) * 64;
  const int l31 = lane & 31, half = lane >> 5;

  // staging sources: per thread 2 chunks of A, 2 of B (512 chunks / 256 threads)
  const ushort* AgB[2]; const ushort* BgB[2]; int AlO[2], BlO[2];
  #pragma unroll
  for (int it=0; it<2; ++it){
    int p  = it*256 + tid;
    int r  = p >> 2;
    int cl = (p & 3) ^ ((r >> 1) & 3);
    AgB[it] = A  + (size_t)(bm*BM + r)*K + cl*8;
    BgB[it] = BT + (size_t)(bn*BN + r)*K + cl*8;
    AlO[it] = p*8;
    BlO[it] = p*8;
  }

  // read-side row bases + swizzle keys
  int arow[2], asz[2], brow[2], bsz[2];
  #pragma unroll
  for (int i=0;i<2;i++){
    int ra = wm + i*32 + l31; arow[i] = ra*BK; asz[i] = (ra >> 1) & 3;
    int rb = wn + i*32 + l31; brow[i] = rb*BK; bsz[i] = (rb >> 1) & 3;
  }

  f32x16 acc[2][2];
  #pragma unroll
  for (int i=0;i<2;i++)
    #pragma unroll
    for (int j=0;j<2;j++)
      #pragma unroll
      for (int r=0;r<16;r++) acc[i][j][r] = 0.f;

  const int KT = K / BK;  // 24

  // prologue: stage kt=0 into buffer 0
  #pragma unroll
  for (int it=0; it<2; ++it){ async_copy16(AgB[it], Asm + AlO[it]); }
  #pragma unroll
  for (int it=0; it<2; ++it){ async_copy16(BgB[it], Bsm + BlO[it]); }

  for (int kt=0; kt<KT; ++kt){
    const int cur = kt & 1;
    const int nxt = cur ^ 1;
    // all waves done reading buf[nxt] (from iter kt-1) before overwriting it
    asm volatile("s_barrier" ::: "memory");
    const int kn = (kt+1 < KT) ? (kt+1)*BK : 0;   // wrap: dead prefetch stays in-bounds
    #pragma unroll
    for (int it=0; it<2; ++it){ async_copy16(AgB[it] + kn, Asm + nxt*BM*BK + AlO[it]); }
    #pragma unroll
    for (int it=0; it<2; ++it){ async_copy16(BgB[it] + kn, Bsm + nxt*BM*BK + BlO[it]); }
    // wait only for buf[cur]'s 4 loads (the 4 just-issued stay in flight)
    asm volatile("s_waitcnt vmcnt(4)" ::: "memory");
    asm volatile("s_barrier" ::: "memory");       // publish buf[cur]

    const ushort* Ab = Asm + cur*BM*BK;
    const ushort* Bb = Bsm + cur*BM*BK;
    #pragma unroll
    for (int s=0; s<2; ++s){
      const int c = s*2 + half;
      bshort8 av[2], bv[2];
      #pragma unroll
      for (int i=0;i<2;i++){
        av[i] = *(const bshort8*)(Ab + arow[i] + ((c ^ asz[i]) << 3));
        bv[i] = *(const bshort8*)(Bb + brow[i] + ((c ^ bsz[i]) << 3));
      }
      acc[0][0] = __builtin_amdgcn_mfma_f32_32x32x16_bf16(av[0], bv[0], acc[0][0], 0,0,0);
      acc[0][1] = __builtin_amdgcn_mfma_f32_32x32x16_bf16(av[0], bv[1], acc[0][1], 0,0,0);
      acc[1][0] = __builtin_amdgcn_mfma_f32_32x32x16_bf16(av[1], bv[0], acc[1][0], 0,0,0);
      acc[1][1] = __builtin_amdgcn_mfma_f32_32x32x16_bf16(av[1], bv[1], acc[1][1], 0,0,0);
    }
  }

  // epilogue: C/D 32x32 layout: col=lane&31, row=(reg&3)+8*(reg>>2)+4*(lane>>5)
  if (MODE==0 && bn < 6){
    #pragma unroll
    for (int i=0;i<2;i++){
      const int Rbase = bm*BM + wm + i*32 + 4*half;
      #pragma unroll
      for (int j=0;j<2;j++){
        const int Cc = bn*BN + wn + j*32 + l31;
        #pragma unroll
        for (int reg=0; reg<16; reg++){
          const int R = Rbase + (reg & 3) + 8*(reg >> 2);
          oxc[(size_t)R*768 + Cc] = f2bf(acc[i][j][reg]);
        }
      }
    }
  } else if (MODE==0){
    #pragma unroll
    for (int i=0;i<2;i++){
      const int Rbase = bm*BM + wm + i*32 + 4*half;
      #pragma unroll
      for (int j=0;j<2;j++){
        const int Cc = bn*BN - 768 + wn + j*32 + l31;
        #pragma unroll
        for (int reg=0; reg<16; reg++){
          const int R = Rbase + (reg & 3) + 8*(reg >> 2);
          oz[(size_t)R*768 + Cc] = f2bf(silu_f(acc[i][j][reg]));
        }
      }
    }
  } else {
    #pragma unroll
    for (int i=0;i<2;i++){
      const int Rbase = bm*BM + wm + i*32 + 4*half;
      #pragma unroll
      for (int j=0;j<2;j++){
        const int Cc = bn*BN + wn + j*32 + l31;
        #pragma unroll
        for (int reg=0; reg<16; reg++){
          const int R = Rbase + (reg & 3) + 8*(reg >> 2);
          of[(size_t)R*768 + Cc] = acc[i][j][reg];
        }
      }
    }
  }
}

// ---------------- pass 1: conv+silu, per-chunk sums (u never stored)
__global__ void conv_psum(const ushort* __restrict__ xc, const float* __restrict__ cw,
                          const float* __restrict__ cb, float* __restrict__ psum){
  int c = blockIdx.y*256 + threadIdx.x;
  int b = blockIdx.z, ch = blockIdx.x;
  int t0 = ch*CHUNK;
  const ushort* xp = xc + (size_t)b*NSEQ*768 + c;
  float w0=cw[c*3+0], w1=cw[c*3+1], w2=cw[c*3+2], bb=cb[c];
  float xm2 = (t0>=2) ? bf2f(xp[(size_t)(t0-2)*768]) : 0.f;
  float xm1 = (t0>=1) ? bf2f(xp[(size_t)(t0-1)*768]) : 0.f;
  float s = 0.f;
  #pragma unroll 4
  for (int i=0;i<CHUNK;i++){
    float x0 = bf2f(xp[(size_t)(t0+i)*768]);
    float pre = w0*xm2 + w1*xm1 + w2*x0 + bb;
    s += silu_f(pre);
    xm2 = xm1; xm1 = x0;
  }
  psum[((size_t)b*NCHUNK + ch)*768 + c] = s;
}

// ---------------- pass 2: exclusive scan of chunk sums per (b,c)
__global__ void scan_chunks(const float* __restrict__ psum, float* __restrict__ offs){
  int idx = blockIdx.x*256 + threadIdx.x; // 0..3071
  int b = idx/768, c = idx%768;
  float run = 0.f;
  for (int ch=0; ch<NCHUNK; ch++){
    size_t o = ((size_t)b*NCHUNK + ch)*768 + c;
    offs[o] = run;
    run += psum[o];
  }
}

// ---------------- pass 3: replay conv+silu with carried offset, apply SSM + gate -> v bf16
__global__ void scan_apply(const ushort* __restrict__ xc, const ushort* __restrict__ zb,
                           const float* __restrict__ cw, const float* __restrict__ cb,
                           const float* __restrict__ Bm, const float* __restrict__ Cm,
                           const float* __restrict__ Dv, const float* __restrict__ offs,
                           ushort* __restrict__ v){
  int c = blockIdx.y*256 + threadIdx.x;
  int b = blockIdx.z, ch = blockIdx.x;
  int t0 = ch*CHUNK;
  size_t base = (size_t)b*NSEQ*768 + c;
  const ushort* xp = xc + base;
  const ushort* zp = zb + base;
  ushort* vp = v + base;
  float w0=cw[c*3+0], w1=cw[c*3+1], w2=cw[c*3+2], bb=cb[c];
  float bc = 0.f;
  #pragma unroll
  for (int s=0;s<8;s++) bc += Bm[c*8+s]*Cm[c*8+s];
  float dd = Dv[c];
  float cum = offs[((size_t)b*NCHUNK + ch)*768 + c];
  float xm2 = (t0>=2) ? bf2f(xp[(size_t)(t0-2)*768]) : 0.f;
  float xm1 = (t0>=1) ? bf2f(xp[(size_t)(t0-1)*768]) : 0.f;
  #pragma unroll 4
  for (int i=0;i<CHUNK;i++){
    size_t o = (size_t)(t0+i)*768;
    float x0 = bf2f(xp[o]);
    float pre = w0*xm2 + w1*xm1 + w2*x0 + bb;
    float u = silu_f(pre);
    cum += u;
    float y = bc*cum + dd*u;
    vp[o] = f2bf(y * bf2f(zp[o]));
    xm2 = xm1; xm1 = x0;
  }
}

extern "C" void kernel_launch(void* const* d_in, const int* in_sizes, int n_in,
                              void* d_out, int out_size, void* d_ws, size_t ws_size,
                              hipStream_t stream)
{
  const float* x      = (const float*)d_in[0];
  const float* W_in   = (const float*)d_in[1];
  const float* conv_w = (const float*)d_in[2];
  const float* conv_b = (const float*)d_in[3];
  const float* Bm     = (const float*)d_in[4];
  const float* Cm     = (const float*)d_in[5];
  const float* Dv     = (const float*)d_in[6];
  const float* W_out  = (const float*)d_in[7];
  float* out = (float*)d_out;

  char* ws = (char*)d_ws;
  ushort* xbf   = (ushort*)(ws + 0);          // 50331648; reused as v after GEMM1
  ushort* xcbf  = (ushort*)(ws + 50331648);   // 50331648
  ushort* zbf   = (ushort*)(ws + 100663296);  // 50331648
  ushort* wint  = (ushort*)(ws + 150994944);  // 2359296
  ushort* woutt = (ushort*)(ws + 153354240);  // 1179648
  float*  psum  = (float*)(ws + 154533888);   // 786432
  float*  offs  = (float*)(ws + 155320320);   // 786432
  if (ws_size < 156106752) return;

  tr_cvt<<<dim3(1536/32, 768/32), 256, 0, stream>>>(W_in,  wint,  768, 1536);
  tr_cvt<<<dim3(768/32,  768/32), 256, 0, stream>>>(W_out, woutt, 768, 768);
  cvt_bf16<<<(MROWS*768)/2048, 256, 0, stream>>>(x, xbf, MROWS*768);

  gemm_bt<0><<<dim3(MROWS/BM, 1536/BN), 256, 0, stream>>>(xbf, wint, xcbf, zbf, nullptr, 768);

  conv_psum  <<<dim3(NCHUNK, 3, NBATCH), 256, 0, stream>>>(xcbf, conv_w, conv_b, psum);
  scan_chunks<<<12, 256, 0, stream>>>(psum, offs);
  scan_apply <<<dim3(NCHUNK, 3, NBATCH), 256, 0, stream>>>(xcbf, zbf, conv_w, conv_b,
                                                           Bm, Cm, Dv, offs, xbf /*v*/);

  gemm_bt<1><<<dim3(MROWS/BM, 768/BN), 256, 0, stream>>>(xbf, woutt, nullptr, nullptr, out, 768);
}

// Round 5
// 407.660 us; speedup vs baseline: 1.0487x; 1.0487x over previous
//
#include <hip/hip_runtime.h>
#include <hip/hip_bf16.h>

#define D_MODEL 768
#define NSEQ    8192
#define NBATCH  4
#define MROWS   (NBATCH*NSEQ)   // 32768
#define CHUNK   128
#define NCHUNK  (NSEQ/CHUNK)    // 64

// GEMM1 tile: BM=128, BN=192, BK=64, 4 waves 2x2, wave tile 64x96
#define BM 128
#define BN 192
#define BK 64

typedef __attribute__((ext_vector_type(8)))  short bshort8;
typedef __attribute__((ext_vector_type(16))) float f32x16;

__device__ __forceinline__ float bf2f(ushort u){
  union { unsigned int i; float f; } x; x.i = ((unsigned int)u) << 16; return x.f;
}
__device__ __forceinline__ ushort f2bf(float f){
  union { float f; unsigned int i; } x; x.f = f;
  unsigned int r = x.i + 0x7fffu + ((x.i >> 16) & 1u);
  return (ushort)(r >> 16);
}
__device__ __forceinline__ float silu_f(float v){ return v / (1.0f + __expf(-v)); }

__device__ __forceinline__ void async_copy16(const ushort* g, ushort* l){
  __builtin_amdgcn_global_load_lds((const __attribute__((address_space(1))) void*)g,
                                   (__attribute__((address_space(3))) void*)l, 16, 0, 0);
}

// ---------------- weight transpose + bf16 convert: in[R][C] f32 -> out[C][R] bf16
__global__ void tr_cvt(const float* __restrict__ in, ushort* __restrict__ out, int R, int C){
  __shared__ float tile[32][33];
  int c0 = blockIdx.x*32, r0 = blockIdx.y*32;
  int tx = threadIdx.x & 31, ty = threadIdx.x >> 5;
  #pragma unroll
  for (int p=0;p<4;p++){
    int r = ty + p*8;
    tile[r][tx] = in[(size_t)(r0+r)*C + c0 + tx];
  }
  __syncthreads();
  #pragma unroll
  for (int p=0;p<4;p++){
    int c = ty + p*8;
    out[(size_t)(c0+c)*R + r0 + tx] = f2bf(tile[tx][c]);
  }
}

// ---------------- x fp32 -> bf16, 8 elems/thread, 16B stores
__global__ void cvt_bf16(const float* __restrict__ in, ushort* __restrict__ out, int n){
  int i = (blockIdx.x*256 + threadIdx.x)*8;
  if (i >= n) return;
  const float4 f0 = *(const float4*)(in + i);
  const float4 f1 = *(const float4*)(in + i + 4);
  ushort o[8];
  o[0]=f2bf(f0.x); o[1]=f2bf(f0.y); o[2]=f2bf(f0.z); o[3]=f2bf(f0.w);
  o[4]=f2bf(f1.x); o[5]=f2bf(f1.y); o[6]=f2bf(f1.z); o[7]=f2bf(f1.w);
  *(ulonglong2*)(out + i) = *(const ulonglong2*)o;
}

// ---------------- GEMM1: 128x192 tile, BK=64, 32x32x16 MFMA, swizzled LDS (round-3 proven).
// A[M][K] bf16 row-major, BT[N][K] bf16 row-major.
// LDS: physical 16B slot p holds logical (row r=p>>3, chunk (p&7)^(r&7)).
// N=1536, block cols uniform: bn<4 -> xc bf16; bn>=4 -> silu -> z bf16
__global__ __launch_bounds__(256) void gemm1_bt(
    const ushort* __restrict__ A, const ushort* __restrict__ BT,
    ushort* __restrict__ oxc, ushort* __restrict__ oz, int K)
{
  __shared__ __align__(16) ushort Asm[BM*BK];   // 16 KB
  __shared__ __align__(16) ushort Bsm[BN*BK];   // 24 KB
  const int tid = threadIdx.x;
  const int bm = blockIdx.x, bn = blockIdx.y;
  const int lane = tid & 63, wid = tid >> 6;
  const int wm = (wid >> 1) * 64, wn = (wid & 1) * 96;
  const int l31 = lane & 31, half = lane >> 5;

  const ushort* Ag[4]; ushort* Al[4];
  #pragma unroll
  for (int it=0; it<4; ++it){
    int p  = it*256 + tid;
    int r  = p >> 3;
    int cl = (p & 7) ^ (r & 7);
    Ag[it] = A + (size_t)(bm*BM + r)*K + cl*8;
    Al[it] = Asm + p*8;
  }
  const ushort* Bg[6]; ushort* Bl[6];
  #pragma unroll
  for (int it=0; it<6; ++it){
    int p  = it*256 + tid;
    int r  = p >> 3;
    int cl = (p & 7) ^ (r & 7);
    Bg[it] = BT + (size_t)(bn*BN + r)*K + cl*8;
    Bl[it] = Bsm + p*8;
  }

  int arow[2], ar7[2], brow[3], br7[3];
  #pragma unroll
  for (int i=0;i<2;i++){
    int ra = wm + i*32 + l31; arow[i] = ra*BK; ar7[i] = ra & 7;
  }
  #pragma unroll
  for (int j=0;j<3;j++){
    int rb = wn + j*32 + l31; brow[j] = rb*BK; br7[j] = rb & 7;
  }

  f32x16 acc[2][3];
  #pragma unroll
  for (int i=0;i<2;i++)
    #pragma unroll
    for (int j=0;j<3;j++)
      #pragma unroll
      for (int r=0;r<16;r++) acc[i][j][r] = 0.f;

  const int KT = K / BK;  // 12
  for (int kt=0; kt<KT; ++kt){
    __syncthreads();
    #pragma unroll
    for (int it=0; it<4; ++it){ async_copy16(Ag[it], Al[it]); Ag[it] += BK; }
    #pragma unroll
    for (int it=0; it<6; ++it){ async_copy16(Bg[it], Bl[it]); Bg[it] += BK; }
    asm volatile("s_waitcnt vmcnt(0)" ::: "memory");
    __syncthreads();

    #pragma unroll
    for (int s=0; s<4; ++s){
      const int c = s*2 + half;
      bshort8 av[2], bv[3];
      #pragma unroll
      for (int i=0;i<2;i++)
        av[i] = *(const bshort8*)(Asm + arow[i] + ((c ^ ar7[i]) << 3));
      #pragma unroll
      for (int j=0;j<3;j++)
        bv[j] = *(const bshort8*)(Bsm + brow[j] + ((c ^ br7[j]) << 3));
      #pragma unroll
      for (int i=0;i<2;i++)
        #pragma unroll
        for (int j=0;j<3;j++)
          acc[i][j] = __builtin_amdgcn_mfma_f32_32x32x16_bf16(av[i], bv[j], acc[i][j], 0,0,0);
    }
  }

  // epilogue: C/D 32x32: col=lane&31, row=(reg&3)+8*(reg>>2)+4*(lane>>5)
  if (bn < 4){
    #pragma unroll
    for (int i=0;i<2;i++){
      const int Rbase = bm*BM + wm + i*32 + 4*half;
      #pragma unroll
      for (int j=0;j<3;j++){
        const int Cc = bn*BN + wn + j*32 + l31;
        #pragma unroll
        for (int reg=0; reg<16; reg++){
          const int R = Rbase + (reg & 3) + 8*(reg >> 2);
          oxc[(size_t)R*768 + Cc] = f2bf(acc[i][j][reg]);
        }
      }
    }
  } else {
    #pragma unroll
    for (int i=0;i<2;i++){
      const int Rbase = bm*BM + wm + i*32 + 4*half;
      #pragma unroll
      for (int j=0;j<3;j++){
        const int Cc = bn*BN - 768 + wn + j*32 + l31;
        #pragma unroll
        for (int reg=0; reg<16; reg++){
          const int R = Rbase + (reg & 3) + 8*(reg >> 2);
          oz[(size_t)R*768 + Cc] = f2bf(silu_f(acc[i][j][reg]));
        }
      }
    }
  }
}

// ---------------- GEMM2: BM=64, BN=192, BK=64, fp32 out. Grid 512x4 = 2048 light blocks.
#define BM2 64
__global__ __launch_bounds__(256) void gemm2_bt(
    const ushort* __restrict__ A, const ushort* __restrict__ BT,
    float* __restrict__ of, int K)
{
  __shared__ __align__(16) ushort Asm[BM2*BK];  // 8 KB
  __shared__ __align__(16) ushort Bsm[BN*BK];   // 24 KB
  const int tid = threadIdx.x;
  const int bm = blockIdx.x, bn = blockIdx.y;
  const int lane = tid & 63, wid = tid >> 6;
  const int wm = (wid >> 1) * 32, wn = (wid & 1) * 96;
  const int l31 = lane & 31, half = lane >> 5;

  const ushort* Ag[2]; ushort* Al[2];
  #pragma unroll
  for (int it=0; it<2; ++it){
    int p  = it*256 + tid;
    int r  = p >> 3;
    int cl = (p & 7) ^ (r & 7);
    Ag[it] = A + (size_t)(bm*BM2 + r)*K + cl*8;
    Al[it] = Asm + p*8;
  }
  const ushort* Bg[6]; ushort* Bl[6];
  #pragma unroll
  for (int it=0; it<6; ++it){
    int p  = it*256 + tid;
    int r  = p >> 3;
    int cl = (p & 7) ^ (r & 7);
    Bg[it] = BT + (size_t)(bn*BN + r)*K + cl*8;
    Bl[it] = Bsm + p*8;
  }

  int arow, ar7, brow[3], br7[3];
  { int ra = wm + l31; arow = ra*BK; ar7 = ra & 7; }
  #pragma unroll
  for (int j=0;j<3;j++){
    int rb = wn + j*32 + l31; brow[j] = rb*BK; br7[j] = rb & 7;
  }

  f32x16 acc[3];
  #pragma unroll
  for (int j=0;j<3;j++)
    #pragma unroll
    for (int r=0;r<16;r++) acc[j][r] = 0.f;

  const int KT = K / BK;  // 12
  for (int kt=0; kt<KT; ++kt){
    __syncthreads();
    #pragma unroll
    for (int it=0; it<2; ++it){ async_copy16(Ag[it], Al[it]); Ag[it] += BK; }
    #pragma unroll
    for (int it=0; it<6; ++it){ async_copy16(Bg[it], Bl[it]); Bg[it] += BK; }
    asm volatile("s_waitcnt vmcnt(0)" ::: "memory");
    __syncthreads();

    #pragma unroll
    for (int s=0; s<4; ++s){
      const int c = s*2 + half;
      bshort8 av, bv[3];
      av = *(const bshort8*)(Asm + arow + ((c ^ ar7) << 3));
      #pragma unroll
      for (int j=0;j<3;j++)
        bv[j] = *(const bshort8*)(Bsm + brow[j] + ((c ^ br7[j]) << 3));
      #pragma unroll
      for (int j=0;j<3;j++)
        acc[j] = __builtin_amdgcn_mfma_f32_32x32x16_bf16(av, bv[j], acc[j], 0,0,0);
    }
  }

  const int Rbase = bm*BM2 + wm + 4*half;
  #pragma unroll
  for (int j=0;j<3;j++){
    const int Cc = bn*BN + wn + j*32 + l31;
    #pragma unroll
    for (int reg=0; reg<16; reg++){
      const int R = Rbase + (reg & 3) + 8*(reg >> 2);
      of[(size_t)R*768 + Cc] = acc[j][reg];
    }
  }
}

// ---------------- pass 1: conv+silu, per-chunk sums; 2 channels/thread, ushort2 loads
__global__ void conv_psum(const ushort* __restrict__ xc, const float* __restrict__ cw,
                          const float* __restrict__ cb, float* __restrict__ psum){
  int c0 = threadIdx.x * 2;               // 0..766
  int b = blockIdx.z, ch = blockIdx.x;
  int t0 = ch*CHUNK;
  const ushort* xp = xc + (size_t)b*NSEQ*768 + c0;
  float w0a=cw[c0*3+0], w1a=cw[c0*3+1], w2a=cw[c0*3+2], ba=cb[c0];
  float w0b=cw[c0*3+3], w1b=cw[c0*3+4], w2b=cw[c0*3+5], bb=cb[c0+1];
  float am2=0.f, am1=0.f, bm2=0.f, bm1=0.f;
  if (t0>=2){ ushort2 u = *(const ushort2*)(xp + (size_t)(t0-2)*768); am2=bf2f(u.x); bm2=bf2f(u.y); }
  if (t0>=1){ ushort2 u = *(const ushort2*)(xp + (size_t)(t0-1)*768); am1=bf2f(u.x); bm1=bf2f(u.y); }
  float sa=0.f, sb=0.f;
  #pragma unroll 4
  for (int i=0;i<CHUNK;i++){
    ushort2 u = *(const ushort2*)(xp + (size_t)(t0+i)*768);
    float xa = bf2f(u.x), xb = bf2f(u.y);
    sa += silu_f(w0a*am2 + w1a*am1 + w2a*xa + ba);
    sb += silu_f(w0b*bm2 + w1b*bm1 + w2b*xb + bb);
    am2=am1; am1=xa; bm2=bm1; bm1=xb;
  }
  float2* pp = (float2*)(psum + ((size_t)b*NCHUNK + ch)*768 + c0);
  *pp = make_float2(sa, sb);
}

// ---------------- pass 2: exclusive scan of chunk sums per (b,c)
__global__ void scan_chunks(const float* __restrict__ psum, float* __restrict__ offs){
  int idx = blockIdx.x*256 + threadIdx.x; // 0..3071
  int b = idx/768, c = idx%768;
  float run = 0.f;
  for (int ch=0; ch<NCHUNK; ch++){
    size_t o = ((size_t)b*NCHUNK + ch)*768 + c;
    offs[o] = run;
    run += psum[o];
  }
}

// ---------------- pass 3: replay conv+silu, apply SSM + gate -> v bf16; 2 ch/thread
__global__ void scan_apply(const ushort* __restrict__ xc, const ushort* __restrict__ zb,
                           const float* __restrict__ cw, const float* __restrict__ cb,
                           const float* __restrict__ Bm, const float* __restrict__ Cm,
                           const float* __restrict__ Dv, const float* __restrict__ offs,
                           ushort* __restrict__ v){
  int c0 = threadIdx.x * 2;
  int b = blockIdx.z, ch = blockIdx.x;
  int t0 = ch*CHUNK;
  size_t base = (size_t)b*NSEQ*768 + c0;
  const ushort* xp = xc + base;
  const ushort* zp = zb + base;
  ushort* vp = v + base;
  float w0a=cw[c0*3+0], w1a=cw[c0*3+1], w2a=cw[c0*3+2], ba=cb[c0];
  float w0b=cw[c0*3+3], w1b=cw[c0*3+4], w2b=cw[c0*3+5], bb=cb[c0+1];
  float bca=0.f, bcb=0.f;
  #pragma unroll
  for (int s=0;s<8;s++){ bca += Bm[c0*8+s]*Cm[c0*8+s]; bcb += Bm[c0*8+8+s]*Cm[c0*8+8+s]; }
  float dda = Dv[c0], ddb = Dv[c0+1];
  const float2 off2 = *(const float2*)(offs + ((size_t)b*NCHUNK + ch)*768 + c0);
  float cua = off2.x, cub = off2.y;
  float am2=0.f, am1=0.f, bm2=0.f, bm1=0.f;
  if (t0>=2){ ushort2 u = *(const ushort2*)(xp + (size_t)(t0-2)*768); am2=bf2f(u.x); bm2=bf2f(u.y); }
  if (t0>=1){ ushort2 u = *(const ushort2*)(xp + (size_t)(t0-1)*768); am1=bf2f(u.x); bm1=bf2f(u.y); }
  #pragma unroll 4
  for (int i=0;i<CHUNK;i++){
    size_t o = (size_t)(t0+i)*768;
    ushort2 u = *(const ushort2*)(xp + o);
    ushort2 z2 = *(const ushort2*)(zp + o);
    float xa = bf2f(u.x), xb = bf2f(u.y);
    float ua = silu_f(w0a*am2 + w1a*am1 + w2a*xa + ba);
    float ub = silu_f(w0b*bm2 + w1b*bm1 + w2b*xb + bb);
    cua += ua; cub += ub;
    float ya = bca*cua + dda*ua;
    float yb = bcb*cub + ddb*ub;
    ushort2 o2; o2.x = f2bf(ya * bf2f(z2.x)); o2.y = f2bf(yb * bf2f(z2.y));
    *(ushort2*)(vp + o) = o2;
    am2=am1; am1=xa; bm2=bm1; bm1=xb;
  }
}

extern "C" void kernel_launch(void* const* d_in, const int* in_sizes, int n_in,
                              void* d_out, int out_size, void* d_ws, size_t ws_size,
                              hipStream_t stream)
{
  const float* x      = (const float*)d_in[0];
  const float* W_in   = (const float*)d_in[1];
  const float* conv_w = (const float*)d_in[2];
  const float* conv_b = (const float*)d_in[3];
  const float* Bm     = (const float*)d_in[4];
  const float* Cm     = (const float*)d_in[5];
  const float* Dv     = (const float*)d_in[6];
  const float* W_out  = (const float*)d_in[7];
  float* out = (float*)d_out;

  char* ws = (char*)d_ws;
  ushort* xbf   = (ushort*)(ws + 0);          // 50331648; reused as v after GEMM1
  ushort* xcbf  = (ushort*)(ws + 50331648);   // 50331648
  ushort* zbf   = (ushort*)(ws + 100663296);  // 50331648
  ushort* wint  = (ushort*)(ws + 150994944);  // 2359296
  ushort* woutt = (ushort*)(ws + 153354240);  // 1179648
  float*  psum  = (float*)(ws + 154533888);   // 786432
  float*  offs  = (float*)(ws + 155320320);   // 786432
  if (ws_size < 156106752) return;

  tr_cvt<<<dim3(1536/32, 768/32), 256, 0, stream>>>(W_in,  wint,  768, 1536);
  tr_cvt<<<dim3(768/32,  768/32), 256, 0, stream>>>(W_out, woutt, 768, 768);
  cvt_bf16<<<(MROWS*768)/2048, 256, 0, stream>>>(x, xbf, MROWS*768);

  gemm1_bt<<<dim3(MROWS/BM, 1536/BN), 256, 0, stream>>>(xbf, wint, xcbf, zbf, 768);

  conv_psum  <<<dim3(NCHUNK, 1, NBATCH), 384, 0, stream>>>(xcbf, conv_w, conv_b, psum);
  scan_chunks<<<12, 256, 0, stream>>>(psum, offs);
  scan_apply <<<dim3(NCHUNK, 1, NBATCH), 384, 0, stream>>>(xcbf, zbf, conv_w, conv_b,
                                                           Bm, Cm, Dv, offs, xbf /*v*/);

  gemm2_bt<<<dim3(MROWS/BM2, 768/BN), 256, 0, stream>>>(xbf, woutt, out, 768);
}